// Round 1
// baseline (1092.419 us; speedup 1.0000x reference)
//
#include <hip/hip_runtime.h>
#include <hip/hip_bf16.h>

#define N_NODES 100000
#define N_EDGES 1250000
#define DIM 64

typedef __attribute__((ext_vector_type(8))) short short8;
typedef __attribute__((ext_vector_type(8))) __bf16 bf16x8;
typedef __attribute__((ext_vector_type(4))) float f32x4;

static __device__ __forceinline__ short f2bf(float f) {
    union { float f; unsigned u; } v; v.f = f;
    unsigned r = (v.u + 0x7fffu + ((v.u >> 16) & 1u)) >> 16;
    return (short)r;
}

// Convert W1/W2 (f32 row-major [64][64], h = x @ W) into bf16 MFMA B-fragment
// order: frag (ct,kt) holds B[k = kt*32 + (lane>>4)*8 + jj][j = ct*16 + (lane&15)],
// stored at wf[layer*4096 + ((ct*2+kt)*64 + lane)*8 + jj].
__global__ __launch_bounds__(256) void prep_w(const float* __restrict__ W1,
                                              const float* __restrict__ W2,
                                              short* __restrict__ wf) {
    int idx = blockIdx.x * 256 + threadIdx.x;   // 0..8191
    int layer = idx >> 12;
    int fi = idx & 4095;
    int fragidx = fi >> 9;          // 0..7  (= ct*2 + kt)
    int lane = (fi >> 3) & 63;
    int jj = fi & 7;
    int ct = fragidx >> 1, kt = fragidx & 1;
    int k = kt * 32 + (lane >> 4) * 8 + jj;
    int j = ct * 16 + (lane & 15);
    const float* W = layer ? W2 : W1;
    wf[idx] = f2bf(W[k * DIM + j]);
}

// Edge scatter: 16 threads per edge, each handles one float4 chunk of the row.
__global__ __launch_bounds__(256) void scatter_edges(const float4* __restrict__ feat4,
                                                     const int* __restrict__ src,
                                                     const int* __restrict__ dst,
                                                     float* __restrict__ neigh) {
    int idx = blockIdx.x * 256 + threadIdx.x;   // grid covers E*16 exactly
    int e = idx >> 4, c = idx & 15;
    int s = src[e], d = dst[e];
    float4 v = feat4[s * 16 + c];
    float* p = neigh + d * 64 + c * 4;
    unsafeAtomicAdd(p + 0, v.x);
    unsafeAtomicAdd(p + 1, v.y);
    unsafeAtomicAdd(p + 2, v.z);
    unsafeAtomicAdd(p + 3, v.w);
}

// Fused: rst = (1+eps)*feat + neigh; h = relu(rst@W1 + b1); out = h@W2 + b2.
// neigh_out is BOTH the neigh input (scatter result) and the final output:
// each wave reads rows [row0, row0+16) then overwrites exactly those rows.
__global__ __launch_bounds__(256) void gin_mlp(const float* __restrict__ feat,
                                               float* __restrict__ neigh_out,
                                               const short* __restrict__ wf,
                                               const float* __restrict__ b1,
                                               const float* __restrict__ b2,
                                               const float* __restrict__ epsp) {
    __shared__ float hbuf[4][16][66];           // per-wave h tile, stride 66 (2-way bank max)

    int lane = threadIdx.x & 63;
    int wv = threadIdx.x >> 6;
    int r = lane & 15, g = lane >> 4;
    int row0 = blockIdx.x * 64 + wv * 16;
    int node = row0 + r;
    bool valid = node < N_NODES;
    float epsv = 1.0f + epsp[0];

    const short8* w1f8 = (const short8*)(wf);
    const short8* w2f8 = (const short8*)(wf + 4096);

    // ---- A fragments for layer 1: rst[r][kt*32 + g*8 + jj]
    short8 a[2];
    if (valid) {
        const float* fp = feat + node * 64 + g * 8;
        const float* np_ = neigh_out + node * 64 + g * 8;
#pragma unroll
        for (int kt = 0; kt < 2; ++kt) {
            float4 f0 = *(const float4*)(fp + kt * 32);
            float4 f1 = *(const float4*)(fp + kt * 32 + 4);
            float4 n0 = *(const float4*)(np_ + kt * 32);
            float4 n1 = *(const float4*)(np_ + kt * 32 + 4);
            float rs[8] = { epsv * f0.x + n0.x, epsv * f0.y + n0.y,
                            epsv * f0.z + n0.z, epsv * f0.w + n0.w,
                            epsv * f1.x + n1.x, epsv * f1.y + n1.y,
                            epsv * f1.z + n1.z, epsv * f1.w + n1.w };
            short8 t;
#pragma unroll
            for (int jj = 0; jj < 8; ++jj) t[jj] = f2bf(rs[jj]);
            a[kt] = t;
        }
    } else {
        short8 z = { 0, 0, 0, 0, 0, 0, 0, 0 };
        a[0] = z; a[1] = z;
    }

    // ---- layer 1: acc[ct] = rst @ W1[:, ct*16..] + b1
    f32x4 acc[4];
#pragma unroll
    for (int ct = 0; ct < 4; ++ct) {
        float bv = b1[ct * 16 + r];
        f32x4 c = { bv, bv, bv, bv };
        c = __builtin_amdgcn_mfma_f32_16x16x32_bf16(
                __builtin_bit_cast(bf16x8, a[0]),
                __builtin_bit_cast(bf16x8, w1f8[(ct * 2 + 0) * 64 + lane]),
                c, 0, 0, 0);
        c = __builtin_amdgcn_mfma_f32_16x16x32_bf16(
                __builtin_bit_cast(bf16x8, a[1]),
                __builtin_bit_cast(bf16x8, w1f8[(ct * 2 + 1) * 64 + lane]),
                c, 0, 0, 0);
        acc[ct] = c;
    }

    // ---- relu + transpose h through LDS (C layout row=(g*4+i), col=ct*16+r)
#pragma unroll
    for (int ct = 0; ct < 4; ++ct)
#pragma unroll
        for (int i = 0; i < 4; ++i)
            hbuf[wv][g * 4 + i][ct * 16 + r] = fmaxf(acc[ct][i], 0.0f);

    __syncthreads();

    // ---- A fragments for layer 2: h[r][kt*32 + g*8 + jj]
    short8 a2[2];
#pragma unroll
    for (int kt = 0; kt < 2; ++kt) {
        const float2* hp = (const float2*)&hbuf[wv][r][kt * 32 + g * 8];
        float2 h0 = hp[0], h1 = hp[1], h2 = hp[2], h3 = hp[3];
        float hs[8] = { h0.x, h0.y, h1.x, h1.y, h2.x, h2.y, h3.x, h3.y };
        short8 t;
#pragma unroll
        for (int jj = 0; jj < 8; ++jj) t[jj] = f2bf(hs[jj]);
        a2[kt] = t;
    }

    // ---- layer 2: out[ct] = h @ W2[:, ct*16..] + b2
    f32x4 acc2[4];
#pragma unroll
    for (int ct = 0; ct < 4; ++ct) {
        float bv = b2[ct * 16 + r];
        f32x4 c = { bv, bv, bv, bv };
        c = __builtin_amdgcn_mfma_f32_16x16x32_bf16(
                __builtin_bit_cast(bf16x8, a2[0]),
                __builtin_bit_cast(bf16x8, w2f8[(ct * 2 + 0) * 64 + lane]),
                c, 0, 0, 0);
        c = __builtin_amdgcn_mfma_f32_16x16x32_bf16(
                __builtin_bit_cast(bf16x8, a2[1]),
                __builtin_bit_cast(bf16x8, w2f8[(ct * 2 + 1) * 64 + lane]),
                c, 0, 0, 0);
        acc2[ct] = c;
    }

    // ---- store: out[row0 + g*4 + i][ct*16 + r]
#pragma unroll
    for (int ct = 0; ct < 4; ++ct)
#pragma unroll
        for (int i = 0; i < 4; ++i) {
            int nrow = row0 + g * 4 + i;
            if (nrow < N_NODES)
                neigh_out[nrow * 64 + ct * 16 + r] = acc2[ct][i];
        }
}

extern "C" void kernel_launch(void* const* d_in, const int* in_sizes, int n_in,
                              void* d_out, int out_size, void* d_ws, size_t ws_size,
                              hipStream_t stream) {
    const float* feat = (const float*)d_in[0];
    const float* W1   = (const float*)d_in[1];
    const float* b1   = (const float*)d_in[2];
    const float* W2   = (const float*)d_in[3];
    const float* b2   = (const float*)d_in[4];
    const float* eps  = (const float*)d_in[5];
    const int*   src  = (const int*)d_in[6];
    const int*   dst  = (const int*)d_in[7];
    float* out = (float*)d_out;
    short* wf  = (short*)d_ws;      // 8192 shorts = 16 KB

    // W fragments (independent of scatter)
    prep_w<<<32, 256, 0, stream>>>(W1, W2, wf);

    // neigh accumulator lives in d_out
    hipMemsetAsync(d_out, 0, (size_t)N_NODES * DIM * sizeof(float), stream);

    // scatter-add: E*16 threads, exact grid
    scatter_edges<<<(N_EDGES * 16) / 256, 256, 0, stream>>>((const float4*)feat, src, dst, out);

    // fused combine + 2-layer MLP (reads d_out as neigh, overwrites with result)
    gin_mlp<<<(N_NODES + 63) / 64, 256, 0, stream>>>(feat, out, wf, b1, b2, eps);
}

// Round 2
// 225.421 us; speedup vs baseline: 4.8461x; 4.8461x over previous
//
#include <hip/hip_runtime.h>
#include <hip/hip_bf16.h>

#define N_NODES 100000
#define N_EDGES 1250000
#define DIM 64
#define SCAN_NB ((N_NODES + 1023) / 1024)   // 98

typedef __attribute__((ext_vector_type(8))) short short8;
typedef __attribute__((ext_vector_type(8))) __bf16 bf16x8;
typedef __attribute__((ext_vector_type(4))) float f32x4;

static __device__ __forceinline__ short f2bf(float f) {
    union { float f; unsigned u; } v; v.f = f;
    unsigned r = (v.u + 0x7fffu + ((v.u >> 16) & 1u)) >> 16;
    return (short)r;
}

// ---------------- W fragment prep (unchanged) ----------------
__global__ __launch_bounds__(256) void prep_w(const float* __restrict__ W1,
                                              const float* __restrict__ W2,
                                              short* __restrict__ wf) {
    int idx = blockIdx.x * 256 + threadIdx.x;   // 0..8191
    int layer = idx >> 12;
    int fi = idx & 4095;
    int fragidx = fi >> 9;
    int lane = (fi >> 3) & 63;
    int jj = fi & 7;
    int ct = fragidx >> 1, kt = fragidx & 1;
    int k = kt * 32 + (lane >> 4) * 8 + jj;
    int j = ct * 16 + (lane & 15);
    const float* W = layer ? W2 : W1;
    wf[idx] = f2bf(W[k * DIM + j]);
}

// ---------------- CSR build ----------------
__global__ __launch_bounds__(256) void hist_dst(const int* __restrict__ dst,
                                                int* __restrict__ counts) {
    int i = blockIdx.x * 256 + threadIdx.x;
    if (i < N_EDGES) atomicAdd(&counts[dst[i]], 1);
}

__global__ __launch_bounds__(256) void scan_blocks(const int* __restrict__ counts,
                                                   int* __restrict__ bsums) {
    __shared__ int red[256];
    int t = threadIdx.x, base = blockIdx.x * 1024;
    int s = 0;
#pragma unroll
    for (int i = 0; i < 4; ++i) {
        int idx = base + t * 4 + i;
        if (idx < N_NODES) s += counts[idx];
    }
    red[t] = s; __syncthreads();
    for (int off = 128; off > 0; off >>= 1) {
        if (t < off) red[t] += red[t + off];
        __syncthreads();
    }
    if (t == 0) bsums[blockIdx.x] = red[0];
}

__global__ __launch_bounds__(128) void scan_bsums(int* __restrict__ bsums) {
    __shared__ int s[128];
    int t = threadIdx.x;
    int v = (t < SCAN_NB) ? bsums[t] : 0;
    s[t] = v; __syncthreads();
    for (int off = 1; off < 128; off <<= 1) {
        int u = (t >= off) ? s[t - off] : 0;
        __syncthreads();
        s[t] += u;
        __syncthreads();
    }
    if (t < SCAN_NB) bsums[t] = s[t] - v;   // exclusive
}

__global__ __launch_bounds__(256) void scan_final(const int* __restrict__ counts,
                                                  const int* __restrict__ bsums,
                                                  int* __restrict__ offsets,
                                                  int* __restrict__ cursor) {
    __shared__ int sc[256];
    int t = threadIdx.x, base = blockIdx.x * 1024;
    int v[4]; int s = 0;
#pragma unroll
    for (int i = 0; i < 4; ++i) {
        int idx = base + t * 4 + i;
        v[i] = (idx < N_NODES) ? counts[idx] : 0;
        s += v[i];
    }
    sc[t] = s; __syncthreads();
    for (int off = 1; off < 256; off <<= 1) {
        int u = (t >= off) ? sc[t - off] : 0;
        __syncthreads();
        sc[t] += u;
        __syncthreads();
    }
    int ex = bsums[blockIdx.x] + sc[t] - s;
#pragma unroll
    for (int i = 0; i < 4; ++i) {
        int idx = base + t * 4 + i;
        if (idx < N_NODES) { offsets[idx] = ex; cursor[idx] = ex; }
        ex += v[i];
    }
}

__global__ __launch_bounds__(256) void scatter_sort(const int* __restrict__ src,
                                                    const int* __restrict__ dst,
                                                    int* __restrict__ cursor,
                                                    int* __restrict__ sorted_src) {
    int i = blockIdx.x * 256 + threadIdx.x;
    if (i < N_EDGES) {
        int d = dst[i];
        int p = atomicAdd(&cursor[d], 1);
        sorted_src[p] = src[i];
    }
}

// ---------------- segmented gather: neigh[node] = sum feat[sorted_src[e]] ----------------
// 16 lanes per node, one float4 chunk each. After scatter_sort, cursor[node] == end offset.
__global__ __launch_bounds__(256) void gather_neigh(const int* __restrict__ offsets,
                                                    const int* __restrict__ ends,
                                                    const int* __restrict__ sorted_src,
                                                    const float4* __restrict__ feat4,
                                                    float4* __restrict__ neigh4) {
    int t = blockIdx.x * 256 + threadIdx.x;
    int node = t >> 4, c = t & 15;
    if (node >= N_NODES) return;
    int b = offsets[node], e = ends[node];
    float4 acc = { 0.f, 0.f, 0.f, 0.f };
    int i = b;
    for (; i + 1 < e; i += 2) {
        int s0 = sorted_src[i], s1 = sorted_src[i + 1];
        float4 v0 = feat4[s0 * 16 + c];
        float4 v1 = feat4[s1 * 16 + c];
        acc.x += v0.x; acc.y += v0.y; acc.z += v0.z; acc.w += v0.w;
        acc.x += v1.x; acc.y += v1.y; acc.z += v1.z; acc.w += v1.w;
    }
    if (i < e) {
        int s0 = sorted_src[i];
        float4 v0 = feat4[s0 * 16 + c];
        acc.x += v0.x; acc.y += v0.y; acc.z += v0.z; acc.w += v0.w;
    }
    neigh4[node * 16 + c] = acc;
}

// ---------------- fallback atomic scatter (if ws too small) ----------------
__global__ __launch_bounds__(256) void scatter_edges(const float4* __restrict__ feat4,
                                                     const int* __restrict__ src,
                                                     const int* __restrict__ dst,
                                                     float* __restrict__ neigh) {
    int idx = blockIdx.x * 256 + threadIdx.x;
    int e = idx >> 4, c = idx & 15;
    int s = src[e], d = dst[e];
    float4 v = feat4[s * 16 + c];
    float* p = neigh + d * 64 + c * 4;
    unsafeAtomicAdd(p + 0, v.x);
    unsafeAtomicAdd(p + 1, v.y);
    unsafeAtomicAdd(p + 2, v.z);
    unsafeAtomicAdd(p + 3, v.w);
}

// ---------------- fused combine + MLP (unchanged) ----------------
__global__ __launch_bounds__(256) void gin_mlp(const float* __restrict__ feat,
                                               float* __restrict__ neigh_out,
                                               const short* __restrict__ wf,
                                               const float* __restrict__ b1,
                                               const float* __restrict__ b2,
                                               const float* __restrict__ epsp) {
    __shared__ float hbuf[4][16][66];

    int lane = threadIdx.x & 63;
    int wv = threadIdx.x >> 6;
    int r = lane & 15, g = lane >> 4;
    int row0 = blockIdx.x * 64 + wv * 16;
    int node = row0 + r;
    bool valid = node < N_NODES;
    float epsv = 1.0f + epsp[0];

    const short8* w1f8 = (const short8*)(wf);
    const short8* w2f8 = (const short8*)(wf + 4096);

    short8 a[2];
    if (valid) {
        const float* fp = feat + node * 64 + g * 8;
        const float* np_ = neigh_out + node * 64 + g * 8;
#pragma unroll
        for (int kt = 0; kt < 2; ++kt) {
            float4 f0 = *(const float4*)(fp + kt * 32);
            float4 f1 = *(const float4*)(fp + kt * 32 + 4);
            float4 n0 = *(const float4*)(np_ + kt * 32);
            float4 n1 = *(const float4*)(np_ + kt * 32 + 4);
            float rs[8] = { epsv * f0.x + n0.x, epsv * f0.y + n0.y,
                            epsv * f0.z + n0.z, epsv * f0.w + n0.w,
                            epsv * f1.x + n1.x, epsv * f1.y + n1.y,
                            epsv * f1.z + n1.z, epsv * f1.w + n1.w };
            short8 t;
#pragma unroll
            for (int jj = 0; jj < 8; ++jj) t[jj] = f2bf(rs[jj]);
            a[kt] = t;
        }
    } else {
        short8 z = { 0, 0, 0, 0, 0, 0, 0, 0 };
        a[0] = z; a[1] = z;
    }

    f32x4 acc[4];
#pragma unroll
    for (int ct = 0; ct < 4; ++ct) {
        float bv = b1[ct * 16 + r];
        f32x4 c = { bv, bv, bv, bv };
        c = __builtin_amdgcn_mfma_f32_16x16x32_bf16(
                __builtin_bit_cast(bf16x8, a[0]),
                __builtin_bit_cast(bf16x8, w1f8[(ct * 2 + 0) * 64 + lane]),
                c, 0, 0, 0);
        c = __builtin_amdgcn_mfma_f32_16x16x32_bf16(
                __builtin_bit_cast(bf16x8, a[1]),
                __builtin_bit_cast(bf16x8, w1f8[(ct * 2 + 1) * 64 + lane]),
                c, 0, 0, 0);
        acc[ct] = c;
    }

#pragma unroll
    for (int ct = 0; ct < 4; ++ct)
#pragma unroll
        for (int i = 0; i < 4; ++i)
            hbuf[wv][g * 4 + i][ct * 16 + r] = fmaxf(acc[ct][i], 0.0f);

    __syncthreads();

    short8 a2[2];
#pragma unroll
    for (int kt = 0; kt < 2; ++kt) {
        const float2* hp = (const float2*)&hbuf[wv][r][kt * 32 + g * 8];
        float2 h0 = hp[0], h1 = hp[1], h2 = hp[2], h3 = hp[3];
        float hs[8] = { h0.x, h0.y, h1.x, h1.y, h2.x, h2.y, h3.x, h3.y };
        short8 t;
#pragma unroll
        for (int jj = 0; jj < 8; ++jj) t[jj] = f2bf(hs[jj]);
        a2[kt] = t;
    }

    f32x4 acc2[4];
#pragma unroll
    for (int ct = 0; ct < 4; ++ct) {
        float bv = b2[ct * 16 + r];
        f32x4 c = { bv, bv, bv, bv };
        c = __builtin_amdgcn_mfma_f32_16x16x32_bf16(
                __builtin_bit_cast(bf16x8, a2[0]),
                __builtin_bit_cast(bf16x8, w2f8[(ct * 2 + 0) * 64 + lane]),
                c, 0, 0, 0);
        c = __builtin_amdgcn_mfma_f32_16x16x32_bf16(
                __builtin_bit_cast(bf16x8, a2[1]),
                __builtin_bit_cast(bf16x8, w2f8[(ct * 2 + 1) * 64 + lane]),
                c, 0, 0, 0);
        acc2[ct] = c;
    }

#pragma unroll
    for (int ct = 0; ct < 4; ++ct)
#pragma unroll
        for (int i = 0; i < 4; ++i) {
            int nrow = row0 + g * 4 + i;
            if (nrow < N_NODES)
                neigh_out[nrow * 64 + ct * 16 + r] = acc2[ct][i];
        }
}

extern "C" void kernel_launch(void* const* d_in, const int* in_sizes, int n_in,
                              void* d_out, int out_size, void* d_ws, size_t ws_size,
                              hipStream_t stream) {
    const float* feat = (const float*)d_in[0];
    const float* W1   = (const float*)d_in[1];
    const float* b1   = (const float*)d_in[2];
    const float* W2   = (const float*)d_in[3];
    const float* b2   = (const float*)d_in[4];
    const float* eps  = (const float*)d_in[5];
    const int*   src  = (const int*)d_in[6];
    const int*   dst  = (const int*)d_in[7];
    float* out = (float*)d_out;

    // workspace layout
    char* ws = (char*)d_ws;
    short* wf      = (short*)ws;                          // 16384 B
    int* counts    = (int*)(ws + 16384);                  // 100000
    int* offsets   = counts + N_NODES;                    // 100000
    int* cursor    = offsets + N_NODES;                   // 100000
    int* bsums     = cursor + N_NODES;                    // 128 (98 used)
    int* sorted    = bsums + 128;                         // 1250000
    size_t needed  = 16384 + sizeof(int) * (size_t)(3 * N_NODES + 128 + N_EDGES);

    prep_w<<<32, 256, 0, stream>>>(W1, W2, wf);

    if (ws_size >= needed) {
        // CSR build: histogram -> scan -> dst-sorted src list
        hipMemsetAsync(counts, 0, N_NODES * sizeof(int), stream);
        hist_dst<<<(N_EDGES + 255) / 256, 256, 0, stream>>>(dst, counts);
        scan_blocks<<<SCAN_NB, 256, 0, stream>>>(counts, bsums);
        scan_bsums<<<1, 128, 0, stream>>>(bsums);
        scan_final<<<SCAN_NB, 256, 0, stream>>>(counts, bsums, offsets, cursor);
        scatter_sort<<<(N_EDGES + 255) / 256, 256, 0, stream>>>(src, dst, cursor, sorted);
        // after scatter_sort, cursor[n] == end offset of node n
        gather_neigh<<<(N_NODES * 16) / 256, 256, 0, stream>>>(
            offsets, cursor, sorted, (const float4*)feat, (float4*)out);
    } else {
        // fallback: atomic scatter into d_out
        hipMemsetAsync(d_out, 0, (size_t)N_NODES * DIM * sizeof(float), stream);
        scatter_edges<<<(N_EDGES * 16) / 256, 256, 0, stream>>>(
            (const float4*)feat, src, dst, out);
    }

    gin_mlp<<<(N_NODES + 63) / 64, 256, 0, stream>>>(feat, out, wf, b1, b2, eps);
}